// Round 6
// baseline (173.347 us; speedup 1.0000x reference)
//
#include <hip/hip_runtime.h>
#include <stdint.h>

#define NTHREADS 256
#define BLOCKS   2048

typedef int   v4i __attribute__((ext_vector_type(4)));
typedef float v4f __attribute__((ext_vector_type(4)));

template<bool NT, typename T>
__device__ __forceinline__ T ldT(const T* p) {
    if constexpr (NT) return __builtin_nontemporal_load(p);
    else              return *p;
}

// ---------------- pack kernel: x[V,3] fp32 -> 10|10|10 fixed in uint32 -------
__global__ __launch_bounds__(NTHREADS) void stvk_pack_x(
    const float* __restrict__ x, uint32_t* __restrict__ xp, int V)
{
    int v = blockIdx.x * NTHREADS + threadIdx.x;
    if (v >= V) return;
    float a = x[3 * v + 0];
    float b = x[3 * v + 1];
    float c = x[3 * v + 2];
    int ua = __float2int_rn(a * 64.0f) + 512;
    int ub = __float2int_rn(b * 64.0f) + 512;
    int uc = __float2int_rn(c * 64.0f) + 512;
    ua = ua < 0 ? 0 : (ua > 1023 ? 1023 : ua);
    ub = ub < 0 ? 0 : (ub > 1023 ? 1023 : ub);
    uc = uc < 0 ? 0 : (uc > 1023 ? 1023 : uc);
    xp[v] = (uint32_t)ua | ((uint32_t)ub << 10) | ((uint32_t)uc << 20);
}

__device__ __forceinline__ float edge_energy(uint32_t wa, uint32_t wb,
                                             float l, float k)
{
    int dx = (int)(wa & 1023u)         - (int)(wb & 1023u);
    int dy = (int)((wa >> 10) & 1023u) - (int)((wb >> 10) & 1023u);
    int dz = (int)((wa >> 20) & 1023u) - (int)((wb >> 20) & 1023u);
    const float s = 1.0f / 64.0f;
    float fx = (float)dx * s;
    float fy = (float)dy * s;
    float fz = (float)dz * s;
    float q  = fx * fx + fy * fy + fz * fz;
    float dq = q - l * l;
    return k * dq * dq;
}

// ---------------- persistent main: 4 edges/unit, grid-stride, NT-gather A/B --
template<bool NTG>
__global__ __launch_bounds__(NTHREADS) void stvk_persist(
    const uint32_t* __restrict__ xp,
    const float*    __restrict__ l0,
    const float*    __restrict__ kst,
    const int*      __restrict__ idx,    // [E,2] int32
    float*          __restrict__ partial,
    int uBeg, int uEnd)                  // unit = 4 edges
{
    const v4i* idx4 = (const v4i*)idx;   // 2 edges per v4i
    const v4f* l4   = (const v4f*)l0;
    const v4f* k4   = (const v4f*)kst;

    int stride = gridDim.x * blockDim.x;
    float acc = 0.0f;

    #pragma unroll 2
    for (int u = uBeg + blockIdx.x * NTHREADS + threadIdx.x; u < uEnd; u += stride) {
        v4i ab = idx4[2 * u];
        v4i cd = idx4[2 * u + 1];

        uint32_t w0 = ldT<NTG>(xp + ab.x);
        uint32_t w1 = ldT<NTG>(xp + ab.y);
        uint32_t w2 = ldT<NTG>(xp + ab.z);
        uint32_t w3 = ldT<NTG>(xp + ab.w);
        uint32_t w4 = ldT<NTG>(xp + cd.x);
        uint32_t w5 = ldT<NTG>(xp + cd.y);
        uint32_t w6 = ldT<NTG>(xp + cd.z);
        uint32_t w7 = ldT<NTG>(xp + cd.w);

        v4f L = l4[u];
        v4f K = k4[u];

        acc += edge_energy(w0, w1, L.x, K.x);
        acc += edge_energy(w2, w3, L.y, K.y);
        acc += edge_energy(w4, w5, L.z, K.z);
        acc += edge_energy(w6, w7, L.w, K.w);
    }

    // wave reduction
    #pragma unroll
    for (int off = 32; off > 0; off >>= 1)
        acc += __shfl_down(acc, off, 64);

    __shared__ float smem[NTHREADS / 64];
    int lane = threadIdx.x & 63;
    int wid  = threadIdx.x >> 6;
    if (lane == 0) smem[wid] = acc;
    __syncthreads();

    if (threadIdx.x == 0) {
        float s = 0.0f;
        #pragma unroll
        for (int wv = 0; wv < NTHREADS / 64; ++wv) s += smem[wv];
        partial[blockIdx.x] = s;
    }
}

// ---------------- fallback (round-2 proven path) -----------------------------
__global__ __launch_bounds__(NTHREADS) void stvk_simple_kernel(
    const float* __restrict__ x,
    const float* __restrict__ l0,
    const float* __restrict__ kst,
    const int*   __restrict__ idx,
    float*       __restrict__ partial,
    int E)
{
    float acc = 0.0f;
    int tid    = blockIdx.x * blockDim.x + threadIdx.x;
    int stride = gridDim.x * blockDim.x;
    const int2* idx2 = (const int2*)idx;
    for (int e = tid; e < E; e += stride) {
        int2 ij = idx2[e];
        const float* p0 = x + 3 * ij.x;
        const float* p1 = x + 3 * ij.y;
        float dx = p0[0] - p1[0];
        float dy = p0[1] - p1[1];
        float dz = p0[2] - p1[2];
        float q  = dx * dx + dy * dy + dz * dz;
        float Lr = l0[e];
        float dq = q - Lr * Lr;
        acc += kst[e] * dq * dq;
    }
    #pragma unroll
    for (int off = 32; off > 0; off >>= 1)
        acc += __shfl_down(acc, off, 64);
    __shared__ float smem[NTHREADS / 64];
    int lane = threadIdx.x & 63;
    int wid  = threadIdx.x >> 6;
    if (lane == 0) smem[wid] = acc;
    __syncthreads();
    if (threadIdx.x == 0) {
        float s = 0.0f;
        #pragma unroll
        for (int wv = 0; wv < NTHREADS / 64; ++wv) s += smem[wv];
        partial[blockIdx.x] = s;
    }
}

// ---------------- final reduce (+ <=3-edge tail) -----------------------------
__global__ __launch_bounds__(NTHREADS) void stvk_final_kernel(
    const float*    __restrict__ partial, int n,
    const uint32_t* __restrict__ xp,
    const float*    __restrict__ l0,
    const float*    __restrict__ kst,
    const int*      __restrict__ idx,
    int eTailBeg, int E,
    float*          __restrict__ out)
{
    float acc = 0.0f;
    if (threadIdx.x == 0 && xp != nullptr) {
        const int2* idx2 = (const int2*)idx;
        for (int e = eTailBeg; e < E; ++e) {
            int2 ij = idx2[e];
            acc += edge_energy(xp[ij.x], xp[ij.y], l0[e], kst[e]);
        }
    }
    for (int i = threadIdx.x; i < n; i += NTHREADS)
        acc += partial[i];
    #pragma unroll
    for (int off = 32; off > 0; off >>= 1)
        acc += __shfl_down(acc, off, 64);
    __shared__ float smem[NTHREADS / 64];
    int lane = threadIdx.x & 63;
    int wid  = threadIdx.x >> 6;
    if (lane == 0) smem[wid] = acc;
    __syncthreads();
    if (threadIdx.x == 0) {
        float s = 0.0f;
        #pragma unroll
        for (int wv = 0; wv < NTHREADS / 64; ++wv) s += smem[wv];
        out[0] = 0.5f * s;
    }
}

extern "C" void kernel_launch(void* const* d_in, const int* in_sizes, int n_in,
                              void* d_out, int out_size, void* d_ws, size_t ws_size,
                              hipStream_t stream) {
    const float* x   = (const float*)d_in[0];   // [V,3] fp32
    const float* l0  = (const float*)d_in[1];   // [E]   fp32
    const float* kst = (const float*)d_in[2];   // [E]   fp32
    const int*   idx = (const int*)d_in[3];     // [E,2] int32

    int E = in_sizes[1];
    int V = in_sizes[0] / 3;

    int nUnits = E / 4;                         // full 4-edge units
    int uMid   = nUnits / 2;

    size_t xpBytes   = (size_t)V * 4;
    size_t needBytes = xpBytes + (size_t)(2 * BLOCKS) * 4;

    float* out = (float*)d_out;

    if (ws_size >= needBytes) {
        uint32_t* xp       = (uint32_t*)d_ws;
        float*    partialA = (float*)((char*)d_ws + xpBytes);
        float*    partialB = partialA + BLOCKS;

        int packBlocks = (V + NTHREADS - 1) / NTHREADS;
        stvk_pack_x<<<packBlocks, NTHREADS, 0, stream>>>(x, xp, V);

        // A: NT gathers (no L1 allocate) on units [0, uMid)
        stvk_persist<true><<<BLOCKS, NTHREADS, 0, stream>>>(
            xp, l0, kst, idx, partialA, 0, uMid);
        // B: regular gathers on units [uMid, nUnits)
        stvk_persist<false><<<BLOCKS, NTHREADS, 0, stream>>>(
            xp, l0, kst, idx, partialB, uMid, nUnits);

        stvk_final_kernel<<<1, NTHREADS, 0, stream>>>(
            partialA, 2 * BLOCKS, xp, l0, kst, idx, 4 * nUnits, E, out);
    } else {
        int blocks = 2048;
        float* partial = (float*)d_ws;   // needs 8 KB
        stvk_simple_kernel<<<blocks, NTHREADS, 0, stream>>>(
            x, l0, kst, idx, partial, E);
        stvk_final_kernel<<<1, NTHREADS, 0, stream>>>(
            partial, blocks, nullptr, l0, kst, idx, E, E, out);
    }
}

// Round 7
// 109.519 us; speedup vs baseline: 1.5828x; 1.5828x over previous
//
#include <hip/hip_runtime.h>
#include <stdint.h>

#define NTHREADS 256
#define BLOCKS   2048

typedef int   v4i __attribute__((ext_vector_type(4)));
typedef float v4f __attribute__((ext_vector_type(4)));

// ---------------- pack kernel: x[V,3] fp32 -> 10|10|10 fixed in uint32 -------
__global__ __launch_bounds__(NTHREADS) void stvk_pack_x(
    const float* __restrict__ x, uint32_t* __restrict__ xp, int V)
{
    int v = blockIdx.x * NTHREADS + threadIdx.x;
    if (v >= V) return;
    float a = x[3 * v + 0];
    float b = x[3 * v + 1];
    float c = x[3 * v + 2];
    int ua = __float2int_rn(a * 64.0f) + 512;
    int ub = __float2int_rn(b * 64.0f) + 512;
    int uc = __float2int_rn(c * 64.0f) + 512;
    ua = ua < 0 ? 0 : (ua > 1023 ? 1023 : ua);
    ub = ub < 0 ? 0 : (ub > 1023 ? 1023 : ub);
    uc = uc < 0 ? 0 : (uc > 1023 ? 1023 : uc);
    xp[v] = (uint32_t)ua | ((uint32_t)ub << 10) | ((uint32_t)uc << 20);
}

__device__ __forceinline__ float edge_energy(uint32_t wa, uint32_t wb,
                                             float l, float k)
{
    int dx = (int)(wa & 1023u)         - (int)(wb & 1023u);
    int dy = (int)((wa >> 10) & 1023u) - (int)((wb >> 10) & 1023u);
    int dz = (int)((wa >> 20) & 1023u) - (int)((wb >> 20) & 1023u);
    const float s = 1.0f / 64.0f;
    float fx = (float)dx * s;
    float fy = (float)dy * s;
    float fz = (float)dz * s;
    float q  = fx * fx + fy * fy + fz * fz;
    float dq = q - l * l;
    return k * dq * dq;
}

// ---------------- variant A: 1 unit (4 edges) per iter — round-6-B replica ---
__global__ __launch_bounds__(NTHREADS) void stvk_b8(
    const uint32_t* __restrict__ xp,
    const float*    __restrict__ l0,
    const float*    __restrict__ kst,
    const int*      __restrict__ idx,
    float*          __restrict__ partial,
    int uBeg, int uEnd)
{
    const v4i* idx4 = (const v4i*)idx;
    const v4f* l4   = (const v4f*)l0;
    const v4f* k4   = (const v4f*)kst;

    int stride = gridDim.x * blockDim.x;
    float acc = 0.0f;

    #pragma unroll 2
    for (int u = uBeg + blockIdx.x * NTHREADS + threadIdx.x; u < uEnd; u += stride) {
        v4i ab = idx4[2 * u];
        v4i cd = idx4[2 * u + 1];

        uint32_t w0 = xp[ab.x];
        uint32_t w1 = xp[ab.y];
        uint32_t w2 = xp[ab.z];
        uint32_t w3 = xp[ab.w];
        uint32_t w4 = xp[cd.x];
        uint32_t w5 = xp[cd.y];
        uint32_t w6 = xp[cd.z];
        uint32_t w7 = xp[cd.w];

        v4f L = l4[u];
        v4f K = k4[u];

        acc += edge_energy(w0, w1, L.x, K.x);
        acc += edge_energy(w2, w3, L.y, K.y);
        acc += edge_energy(w4, w5, L.z, K.z);
        acc += edge_energy(w6, w7, L.w, K.w);
    }

    #pragma unroll
    for (int off = 32; off > 0; off >>= 1)
        acc += __shfl_down(acc, off, 64);

    __shared__ float smem[NTHREADS / 64];
    int lane = threadIdx.x & 63;
    int wid  = threadIdx.x >> 6;
    if (lane == 0) smem[wid] = acc;
    __syncthreads();

    if (threadIdx.x == 0) {
        float s = 0.0f;
        #pragma unroll
        for (int wv = 0; wv < NTHREADS / 64; ++wv) s += smem[wv];
        partial[blockIdx.x] = s;
    }
}

// ---------------- variant B: 2 units blocked per iter (16 gathers in flight) -
__global__ __launch_bounds__(NTHREADS) void stvk_b16(
    const uint32_t* __restrict__ xp,
    const float*    __restrict__ l0,
    const float*    __restrict__ kst,
    const int*      __restrict__ idx,
    float*          __restrict__ partial,
    int uBeg, int uEnd)
{
    const v4i* idx4 = (const v4i*)idx;
    const v4f* l4   = (const v4f*)l0;
    const v4f* k4   = (const v4f*)kst;

    int stride = gridDim.x * blockDim.x;
    float acc = 0.0f;

    int u = uBeg + blockIdx.x * NTHREADS + threadIdx.x;

    for (; u + stride < uEnd; u += 2 * stride) {
        int u1 = u + stride;
        v4i ab0 = idx4[2 * u];
        v4i cd0 = idx4[2 * u + 1];
        v4i ab1 = idx4[2 * u1];
        v4i cd1 = idx4[2 * u1 + 1];

        uint32_t a0 = xp[ab0.x], a1 = xp[ab0.y], a2 = xp[ab0.z], a3 = xp[ab0.w];
        uint32_t a4 = xp[cd0.x], a5 = xp[cd0.y], a6 = xp[cd0.z], a7 = xp[cd0.w];
        uint32_t b0 = xp[ab1.x], b1 = xp[ab1.y], b2 = xp[ab1.z], b3 = xp[ab1.w];
        uint32_t b4 = xp[cd1.x], b5 = xp[cd1.y], b6 = xp[cd1.z], b7 = xp[cd1.w];

        v4f L0 = l4[u],  K0 = k4[u];
        v4f L1 = l4[u1], K1 = k4[u1];

        acc += edge_energy(a0, a1, L0.x, K0.x);
        acc += edge_energy(a2, a3, L0.y, K0.y);
        acc += edge_energy(a4, a5, L0.z, K0.z);
        acc += edge_energy(a6, a7, L0.w, K0.w);
        acc += edge_energy(b0, b1, L1.x, K1.x);
        acc += edge_energy(b2, b3, L1.y, K1.y);
        acc += edge_energy(b4, b5, L1.z, K1.z);
        acc += edge_energy(b6, b7, L1.w, K1.w);
    }
    for (; u < uEnd; u += stride) {
        v4i ab = idx4[2 * u];
        v4i cd = idx4[2 * u + 1];
        uint32_t w0 = xp[ab.x], w1 = xp[ab.y], w2 = xp[ab.z], w3 = xp[ab.w];
        uint32_t w4 = xp[cd.x], w5 = xp[cd.y], w6 = xp[cd.z], w7 = xp[cd.w];
        v4f L = l4[u];
        v4f K = k4[u];
        acc += edge_energy(w0, w1, L.x, K.x);
        acc += edge_energy(w2, w3, L.y, K.y);
        acc += edge_energy(w4, w5, L.z, K.z);
        acc += edge_energy(w6, w7, L.w, K.w);
    }

    #pragma unroll
    for (int off = 32; off > 0; off >>= 1)
        acc += __shfl_down(acc, off, 64);

    __shared__ float smem[NTHREADS / 64];
    int lane = threadIdx.x & 63;
    int wid  = threadIdx.x >> 6;
    if (lane == 0) smem[wid] = acc;
    __syncthreads();

    if (threadIdx.x == 0) {
        float s = 0.0f;
        #pragma unroll
        for (int wv = 0; wv < NTHREADS / 64; ++wv) s += smem[wv];
        partial[blockIdx.x] = s;
    }
}

// ---------------- fallback (round-2 proven path) -----------------------------
__global__ __launch_bounds__(NTHREADS) void stvk_simple_kernel(
    const float* __restrict__ x,
    const float* __restrict__ l0,
    const float* __restrict__ kst,
    const int*   __restrict__ idx,
    float*       __restrict__ partial,
    int E)
{
    float acc = 0.0f;
    int tid    = blockIdx.x * blockDim.x + threadIdx.x;
    int stride = gridDim.x * blockDim.x;
    const int2* idx2 = (const int2*)idx;
    for (int e = tid; e < E; e += stride) {
        int2 ij = idx2[e];
        const float* p0 = x + 3 * ij.x;
        const float* p1 = x + 3 * ij.y;
        float dx = p0[0] - p1[0];
        float dy = p0[1] - p1[1];
        float dz = p0[2] - p1[2];
        float q  = dx * dx + dy * dy + dz * dz;
        float Lr = l0[e];
        float dq = q - Lr * Lr;
        acc += kst[e] * dq * dq;
    }
    #pragma unroll
    for (int off = 32; off > 0; off >>= 1)
        acc += __shfl_down(acc, off, 64);
    __shared__ float smem[NTHREADS / 64];
    int lane = threadIdx.x & 63;
    int wid  = threadIdx.x >> 6;
    if (lane == 0) smem[wid] = acc;
    __syncthreads();
    if (threadIdx.x == 0) {
        float s = 0.0f;
        #pragma unroll
        for (int wv = 0; wv < NTHREADS / 64; ++wv) s += smem[wv];
        partial[blockIdx.x] = s;
    }
}

// ---------------- final reduce (+ <=3-edge tail) -----------------------------
__global__ __launch_bounds__(NTHREADS) void stvk_final_kernel(
    const float*    __restrict__ partial, int n,
    const uint32_t* __restrict__ xp,
    const float*    __restrict__ l0,
    const float*    __restrict__ kst,
    const int*      __restrict__ idx,
    int eTailBeg, int E,
    float*          __restrict__ out)
{
    float acc = 0.0f;
    if (threadIdx.x == 0 && xp != nullptr) {
        const int2* idx2 = (const int2*)idx;
        for (int e = eTailBeg; e < E; ++e) {
            int2 ij = idx2[e];
            acc += edge_energy(xp[ij.x], xp[ij.y], l0[e], kst[e]);
        }
    }
    for (int i = threadIdx.x; i < n; i += NTHREADS)
        acc += partial[i];
    #pragma unroll
    for (int off = 32; off > 0; off >>= 1)
        acc += __shfl_down(acc, off, 64);
    __shared__ float smem[NTHREADS / 64];
    int lane = threadIdx.x & 63;
    int wid  = threadIdx.x >> 6;
    if (lane == 0) smem[wid] = acc;
    __syncthreads();
    if (threadIdx.x == 0) {
        float s = 0.0f;
        #pragma unroll
        for (int wv = 0; wv < NTHREADS / 64; ++wv) s += smem[wv];
        out[0] = 0.5f * s;
    }
}

extern "C" void kernel_launch(void* const* d_in, const int* in_sizes, int n_in,
                              void* d_out, int out_size, void* d_ws, size_t ws_size,
                              hipStream_t stream) {
    const float* x   = (const float*)d_in[0];   // [V,3] fp32
    const float* l0  = (const float*)d_in[1];   // [E]   fp32
    const float* kst = (const float*)d_in[2];   // [E]   fp32
    const int*   idx = (const int*)d_in[3];     // [E,2] int32

    int E = in_sizes[1];
    int V = in_sizes[0] / 3;

    int nUnits = E / 4;                         // full 4-edge units
    int uMid   = nUnits / 2;

    size_t xpBytes   = (size_t)V * 4;
    size_t needBytes = xpBytes + (size_t)(2 * BLOCKS) * 4;

    float* out = (float*)d_out;

    if (ws_size >= needBytes) {
        uint32_t* xp       = (uint32_t*)d_ws;
        float*    partialA = (float*)((char*)d_ws + xpBytes);
        float*    partialB = partialA + BLOCKS;

        int packBlocks = (V + NTHREADS - 1) / NTHREADS;
        stvk_pack_x<<<packBlocks, NTHREADS, 0, stream>>>(x, xp, V);

        // A: 8 gathers/iter (round-6-B replica) on units [0, uMid)
        stvk_b8<<<BLOCKS, NTHREADS, 0, stream>>>(
            xp, l0, kst, idx, partialA, 0, uMid);
        // B: 16 gathers/iter blocked on units [uMid, nUnits)
        stvk_b16<<<BLOCKS, NTHREADS, 0, stream>>>(
            xp, l0, kst, idx, partialB, uMid, nUnits);

        stvk_final_kernel<<<1, NTHREADS, 0, stream>>>(
            partialA, 2 * BLOCKS, xp, l0, kst, idx, 4 * nUnits, E, out);
    } else {
        int blocks = 2048;
        float* partial = (float*)d_ws;   // needs 8 KB
        stvk_simple_kernel<<<blocks, NTHREADS, 0, stream>>>(
            x, l0, kst, idx, partial, E);
        stvk_final_kernel<<<1, NTHREADS, 0, stream>>>(
            partial, blocks, nullptr, l0, kst, idx, E, E, out);
    }
}

// Round 8
// 108.737 us; speedup vs baseline: 1.5942x; 1.0072x over previous
//
#include <hip/hip_runtime.h>
#include <stdint.h>

#define NTHREADS 256
#define BLOCKS   2048

typedef int   v4i __attribute__((ext_vector_type(4)));
typedef float v4f __attribute__((ext_vector_type(4)));

// ---------------- pack kernel: x[V,3] fp32 -> 10|10|10 fixed in uint32 -------
__global__ __launch_bounds__(NTHREADS) void stvk_pack_x(
    const float* __restrict__ x, uint32_t* __restrict__ xp, int V)
{
    int v = blockIdx.x * NTHREADS + threadIdx.x;
    if (v >= V) return;
    float a = x[3 * v + 0];
    float b = x[3 * v + 1];
    float c = x[3 * v + 2];
    int ua = __float2int_rn(a * 64.0f) + 512;
    int ub = __float2int_rn(b * 64.0f) + 512;
    int uc = __float2int_rn(c * 64.0f) + 512;
    ua = ua < 0 ? 0 : (ua > 1023 ? 1023 : ua);
    ub = ub < 0 ? 0 : (ub > 1023 ? 1023 : ub);
    uc = uc < 0 ? 0 : (uc > 1023 ? 1023 : uc);
    xp[v] = (uint32_t)ua | ((uint32_t)ub << 10) | ((uint32_t)uc << 20);
}

__device__ __forceinline__ float edge_energy(uint32_t wa, uint32_t wb,
                                             float l, float k)
{
    int dx = (int)(wa & 1023u)         - (int)(wb & 1023u);
    int dy = (int)((wa >> 10) & 1023u) - (int)((wb >> 10) & 1023u);
    int dz = (int)((wa >> 20) & 1023u) - (int)((wb >> 20) & 1023u);
    const float s = 1.0f / 64.0f;
    float fx = (float)dx * s;
    float fy = (float)dy * s;
    float fz = (float)dz * s;
    float q  = fx * fx + fy * fy + fz * fz;
    float dq = q - l * l;
    return k * dq * dq;
}

// gather load: plain (L1-cached) or agent-scope (L1 bypass, L2 served)
template<bool AGENT>
__device__ __forceinline__ uint32_t gld(const uint32_t* p) {
    if constexpr (AGENT)
        return __hip_atomic_load(p, __ATOMIC_RELAXED, __HIP_MEMORY_SCOPE_AGENT);
    else
        return *p;
}

// ---------------- persistent main: 4 edges/iter, A/B on gather cache scope ---
template<bool AGENT>
__global__ __launch_bounds__(NTHREADS) void stvk_gather(
    const uint32_t* __restrict__ xp,
    const float*    __restrict__ l0,
    const float*    __restrict__ kst,
    const int*      __restrict__ idx,
    float*          __restrict__ partial,
    int uBeg, int uEnd)
{
    const v4i* idx4 = (const v4i*)idx;
    const v4f* l4   = (const v4f*)l0;
    const v4f* k4   = (const v4f*)kst;

    int stride = gridDim.x * blockDim.x;
    float acc = 0.0f;

    #pragma unroll 2
    for (int u = uBeg + blockIdx.x * NTHREADS + threadIdx.x; u < uEnd; u += stride) {
        v4i ab = idx4[2 * u];
        v4i cd = idx4[2 * u + 1];

        uint32_t w0 = gld<AGENT>(xp + ab.x);
        uint32_t w1 = gld<AGENT>(xp + ab.y);
        uint32_t w2 = gld<AGENT>(xp + ab.z);
        uint32_t w3 = gld<AGENT>(xp + ab.w);
        uint32_t w4 = gld<AGENT>(xp + cd.x);
        uint32_t w5 = gld<AGENT>(xp + cd.y);
        uint32_t w6 = gld<AGENT>(xp + cd.z);
        uint32_t w7 = gld<AGENT>(xp + cd.w);

        v4f L = l4[u];
        v4f K = k4[u];

        acc += edge_energy(w0, w1, L.x, K.x);
        acc += edge_energy(w2, w3, L.y, K.y);
        acc += edge_energy(w4, w5, L.z, K.z);
        acc += edge_energy(w6, w7, L.w, K.w);
    }

    #pragma unroll
    for (int off = 32; off > 0; off >>= 1)
        acc += __shfl_down(acc, off, 64);

    __shared__ float smem[NTHREADS / 64];
    int lane = threadIdx.x & 63;
    int wid  = threadIdx.x >> 6;
    if (lane == 0) smem[wid] = acc;
    __syncthreads();

    if (threadIdx.x == 0) {
        float s = 0.0f;
        #pragma unroll
        for (int wv = 0; wv < NTHREADS / 64; ++wv) s += smem[wv];
        partial[blockIdx.x] = s;
    }
}

// ---------------- fallback (round-2 proven path) -----------------------------
__global__ __launch_bounds__(NTHREADS) void stvk_simple_kernel(
    const float* __restrict__ x,
    const float* __restrict__ l0,
    const float* __restrict__ kst,
    const int*   __restrict__ idx,
    float*       __restrict__ partial,
    int E)
{
    float acc = 0.0f;
    int tid    = blockIdx.x * blockDim.x + threadIdx.x;
    int stride = gridDim.x * blockDim.x;
    const int2* idx2 = (const int2*)idx;
    for (int e = tid; e < E; e += stride) {
        int2 ij = idx2[e];
        const float* p0 = x + 3 * ij.x;
        const float* p1 = x + 3 * ij.y;
        float dx = p0[0] - p1[0];
        float dy = p0[1] - p1[1];
        float dz = p0[2] - p1[2];
        float q  = dx * dx + dy * dy + dz * dz;
        float Lr = l0[e];
        float dq = q - Lr * Lr;
        acc += kst[e] * dq * dq;
    }
    #pragma unroll
    for (int off = 32; off > 0; off >>= 1)
        acc += __shfl_down(acc, off, 64);
    __shared__ float smem[NTHREADS / 64];
    int lane = threadIdx.x & 63;
    int wid  = threadIdx.x >> 6;
    if (lane == 0) smem[wid] = acc;
    __syncthreads();
    if (threadIdx.x == 0) {
        float s = 0.0f;
        #pragma unroll
        for (int wv = 0; wv < NTHREADS / 64; ++wv) s += smem[wv];
        partial[blockIdx.x] = s;
    }
}

// ---------------- final reduce (+ <=3-edge tail) -----------------------------
__global__ __launch_bounds__(NTHREADS) void stvk_final_kernel(
    const float*    __restrict__ partial, int n,
    const uint32_t* __restrict__ xp,
    const float*    __restrict__ l0,
    const float*    __restrict__ kst,
    const int*      __restrict__ idx,
    int eTailBeg, int E,
    float*          __restrict__ out)
{
    float acc = 0.0f;
    if (threadIdx.x == 0 && xp != nullptr) {
        const int2* idx2 = (const int2*)idx;
        for (int e = eTailBeg; e < E; ++e) {
            int2 ij = idx2[e];
            acc += edge_energy(xp[ij.x], xp[ij.y], l0[e], kst[e]);
        }
    }
    for (int i = threadIdx.x; i < n; i += NTHREADS)
        acc += partial[i];
    #pragma unroll
    for (int off = 32; off > 0; off >>= 1)
        acc += __shfl_down(acc, off, 64);
    __shared__ float smem[NTHREADS / 64];
    int lane = threadIdx.x & 63;
    int wid  = threadIdx.x >> 6;
    if (lane == 0) smem[wid] = acc;
    __syncthreads();
    if (threadIdx.x == 0) {
        float s = 0.0f;
        #pragma unroll
        for (int wv = 0; wv < NTHREADS / 64; ++wv) s += smem[wv];
        out[0] = 0.5f * s;
    }
}

extern "C" void kernel_launch(void* const* d_in, const int* in_sizes, int n_in,
                              void* d_out, int out_size, void* d_ws, size_t ws_size,
                              hipStream_t stream) {
    const float* x   = (const float*)d_in[0];   // [V,3] fp32
    const float* l0  = (const float*)d_in[1];   // [E]   fp32
    const float* kst = (const float*)d_in[2];   // [E]   fp32
    const int*   idx = (const int*)d_in[3];     // [E,2] int32

    int E = in_sizes[1];
    int V = in_sizes[0] / 3;

    int nUnits = E / 4;                         // full 4-edge units
    int uMid   = nUnits / 2;

    size_t xpBytes   = (size_t)V * 4;
    size_t needBytes = xpBytes + (size_t)(2 * BLOCKS) * 4;

    float* out = (float*)d_out;

    if (ws_size >= needBytes) {
        uint32_t* xp       = (uint32_t*)d_ws;
        float*    partialA = (float*)((char*)d_ws + xpBytes);
        float*    partialB = partialA + BLOCKS;

        int packBlocks = (V + NTHREADS - 1) / NTHREADS;
        stvk_pack_x<<<packBlocks, NTHREADS, 0, stream>>>(x, xp, V);

        // A: plain gathers (L1-cached) on units [0, uMid)
        stvk_gather<false><<<BLOCKS, NTHREADS, 0, stream>>>(
            xp, l0, kst, idx, partialA, 0, uMid);
        // B: agent-scope gathers (L1 bypass, L2-served) on units [uMid, nUnits)
        stvk_gather<true><<<BLOCKS, NTHREADS, 0, stream>>>(
            xp, l0, kst, idx, partialB, uMid, nUnits);

        stvk_final_kernel<<<1, NTHREADS, 0, stream>>>(
            partialA, 2 * BLOCKS, xp, l0, kst, idx, 4 * nUnits, E, out);
    } else {
        int blocks = 2048;
        float* partial = (float*)d_ws;   // needs 8 KB
        stvk_simple_kernel<<<blocks, NTHREADS, 0, stream>>>(
            x, l0, kst, idx, partial, E);
        stvk_final_kernel<<<1, NTHREADS, 0, stream>>>(
            partial, blocks, nullptr, l0, kst, idx, E, E, out);
    }
}

// Round 9
// 101.629 us; speedup vs baseline: 1.7057x; 1.0699x over previous
//
#include <hip/hip_runtime.h>
#include <stdint.h>

#define NTHREADS 256
#define BLOCKS   2048

typedef int   v4i __attribute__((ext_vector_type(4)));
typedef float v4f __attribute__((ext_vector_type(4)));

// ---------------- pack kernel: x[V,3] fp32 -> 10|10|10 fixed in uint32 -------
__global__ __launch_bounds__(NTHREADS) void stvk_pack_x(
    const float* __restrict__ x, uint32_t* __restrict__ xp, int V)
{
    int v = blockIdx.x * NTHREADS + threadIdx.x;
    if (v >= V) return;
    float a = x[3 * v + 0];
    float b = x[3 * v + 1];
    float c = x[3 * v + 2];
    int ua = __float2int_rn(a * 64.0f) + 512;
    int ub = __float2int_rn(b * 64.0f) + 512;
    int uc = __float2int_rn(c * 64.0f) + 512;
    ua = ua < 0 ? 0 : (ua > 1023 ? 1023 : ua);
    ub = ub < 0 ? 0 : (ub > 1023 ? 1023 : ub);
    uc = uc < 0 ? 0 : (uc > 1023 ? 1023 : uc);
    xp[v] = (uint32_t)ua | ((uint32_t)ub << 10) | ((uint32_t)uc << 20);
}

__device__ __forceinline__ float edge_energy(uint32_t wa, uint32_t wb,
                                             float l, float k)
{
    int dx = (int)(wa & 1023u)         - (int)(wb & 1023u);
    int dy = (int)((wa >> 10) & 1023u) - (int)((wb >> 10) & 1023u);
    int dz = (int)((wa >> 20) & 1023u) - (int)((wb >> 20) & 1023u);
    const float s = 1.0f / 64.0f;
    float fx = (float)dx * s;
    float fy = (float)dy * s;
    float fz = (float)dz * s;
    float q  = fx * fx + fy * fy + fz * fz;
    float dq = q - l * l;
    return k * dq * dq;
}

// ---------------- main: persistent grid-stride, 4 edges/iter, 8 gathers ------
__global__ __launch_bounds__(NTHREADS) void stvk_main(
    const uint32_t* __restrict__ xp,
    const float*    __restrict__ l0,
    const float*    __restrict__ kst,
    const int*      __restrict__ idx,
    float*          __restrict__ partial,
    int nUnits)
{
    const v4i* idx4 = (const v4i*)idx;
    const v4f* l4   = (const v4f*)l0;
    const v4f* k4   = (const v4f*)kst;

    int stride = gridDim.x * blockDim.x;
    float acc = 0.0f;

    #pragma unroll 2
    for (int u = blockIdx.x * NTHREADS + threadIdx.x; u < nUnits; u += stride) {
        v4i ab = idx4[2 * u];
        v4i cd = idx4[2 * u + 1];

        uint32_t w0 = xp[ab.x];
        uint32_t w1 = xp[ab.y];
        uint32_t w2 = xp[ab.z];
        uint32_t w3 = xp[ab.w];
        uint32_t w4 = xp[cd.x];
        uint32_t w5 = xp[cd.y];
        uint32_t w6 = xp[cd.z];
        uint32_t w7 = xp[cd.w];

        v4f L = l4[u];
        v4f K = k4[u];

        acc += edge_energy(w0, w1, L.x, K.x);
        acc += edge_energy(w2, w3, L.y, K.y);
        acc += edge_energy(w4, w5, L.z, K.z);
        acc += edge_energy(w6, w7, L.w, K.w);
    }

    #pragma unroll
    for (int off = 32; off > 0; off >>= 1)
        acc += __shfl_down(acc, off, 64);

    __shared__ float smem[NTHREADS / 64];
    int lane = threadIdx.x & 63;
    int wid  = threadIdx.x >> 6;
    if (lane == 0) smem[wid] = acc;
    __syncthreads();

    if (threadIdx.x == 0) {
        float s = 0.0f;
        #pragma unroll
        for (int wv = 0; wv < NTHREADS / 64; ++wv) s += smem[wv];
        partial[blockIdx.x] = s;
    }
}

// ---------------- fallback (round-2 proven path) -----------------------------
__global__ __launch_bounds__(NTHREADS) void stvk_simple_kernel(
    const float* __restrict__ x,
    const float* __restrict__ l0,
    const float* __restrict__ kst,
    const int*   __restrict__ idx,
    float*       __restrict__ partial,
    int E)
{
    float acc = 0.0f;
    int tid    = blockIdx.x * blockDim.x + threadIdx.x;
    int stride = gridDim.x * blockDim.x;
    const int2* idx2 = (const int2*)idx;
    for (int e = tid; e < E; e += stride) {
        int2 ij = idx2[e];
        const float* p0 = x + 3 * ij.x;
        const float* p1 = x + 3 * ij.y;
        float dx = p0[0] - p1[0];
        float dy = p0[1] - p1[1];
        float dz = p0[2] - p1[2];
        float q  = dx * dx + dy * dy + dz * dz;
        float Lr = l0[e];
        float dq = q - Lr * Lr;
        acc += kst[e] * dq * dq;
    }
    #pragma unroll
    for (int off = 32; off > 0; off >>= 1)
        acc += __shfl_down(acc, off, 64);
    __shared__ float smem[NTHREADS / 64];
    int lane = threadIdx.x & 63;
    int wid  = threadIdx.x >> 6;
    if (lane == 0) smem[wid] = acc;
    __syncthreads();
    if (threadIdx.x == 0) {
        float s = 0.0f;
        #pragma unroll
        for (int wv = 0; wv < NTHREADS / 64; ++wv) s += smem[wv];
        partial[blockIdx.x] = s;
    }
}

// ---------------- final reduce (+ <=3-edge tail) -----------------------------
__global__ __launch_bounds__(NTHREADS) void stvk_final_kernel(
    const float*    __restrict__ partial, int n,
    const uint32_t* __restrict__ xp,
    const float*    __restrict__ l0,
    const float*    __restrict__ kst,
    const int*      __restrict__ idx,
    int eTailBeg, int E,
    float*          __restrict__ out)
{
    float acc = 0.0f;
    if (threadIdx.x == 0 && xp != nullptr) {
        const int2* idx2 = (const int2*)idx;
        for (int e = eTailBeg; e < E; ++e) {
            int2 ij = idx2[e];
            acc += edge_energy(xp[ij.x], xp[ij.y], l0[e], kst[e]);
        }
    }
    for (int i = threadIdx.x; i < n; i += NTHREADS)
        acc += partial[i];
    #pragma unroll
    for (int off = 32; off > 0; off >>= 1)
        acc += __shfl_down(acc, off, 64);
    __shared__ float smem[NTHREADS / 64];
    int lane = threadIdx.x & 63;
    int wid  = threadIdx.x >> 6;
    if (lane == 0) smem[wid] = acc;
    __syncthreads();
    if (threadIdx.x == 0) {
        float s = 0.0f;
        #pragma unroll
        for (int wv = 0; wv < NTHREADS / 64; ++wv) s += smem[wv];
        out[0] = 0.5f * s;
    }
}

extern "C" void kernel_launch(void* const* d_in, const int* in_sizes, int n_in,
                              void* d_out, int out_size, void* d_ws, size_t ws_size,
                              hipStream_t stream) {
    const float* x   = (const float*)d_in[0];   // [V,3] fp32
    const float* l0  = (const float*)d_in[1];   // [E]   fp32
    const float* kst = (const float*)d_in[2];   // [E]   fp32
    const int*   idx = (const int*)d_in[3];     // [E,2] int32

    int E = in_sizes[1];
    int V = in_sizes[0] / 3;

    int nUnits = E / 4;                         // full 4-edge units

    size_t xpBytes   = (size_t)V * 4;
    size_t needBytes = xpBytes + (size_t)BLOCKS * 4;

    float* out = (float*)d_out;

    if (ws_size >= needBytes) {
        uint32_t* xp      = (uint32_t*)d_ws;
        float*    partial = (float*)((char*)d_ws + xpBytes);

        int packBlocks = (V + NTHREADS - 1) / NTHREADS;
        stvk_pack_x<<<packBlocks, NTHREADS, 0, stream>>>(x, xp, V);

        stvk_main<<<BLOCKS, NTHREADS, 0, stream>>>(
            xp, l0, kst, idx, partial, nUnits);

        stvk_final_kernel<<<1, NTHREADS, 0, stream>>>(
            partial, BLOCKS, xp, l0, kst, idx, 4 * nUnits, E, out);
    } else {
        int blocks = 2048;
        float* partial = (float*)d_ws;   // needs 8 KB
        stvk_simple_kernel<<<blocks, NTHREADS, 0, stream>>>(
            x, l0, kst, idx, partial, E);
        stvk_final_kernel<<<1, NTHREADS, 0, stream>>>(
            partial, blocks, nullptr, l0, kst, idx, E, E, out);
    }
}